// Round 5
// baseline (422.653 us; speedup 1.0000x reference)
//
#include <hip/hip_runtime.h>

#define NFEAT 128
#define RS 256   // combined-plane row stride in shorts: [0,128)=H, [128,256)=L

using bf16x8 = __attribute__((ext_vector_type(8))) short;
using f32x4  = __attribute__((ext_vector_type(4))) float;

__device__ __forceinline__ float bf2f(unsigned short u) {
    union { unsigned int i; float f; } v; v.i = ((unsigned int)u) << 16; return v.f;
}
__device__ __forceinline__ float bfhi2f(unsigned int hi16) {
    union { unsigned int i; float f; } v; v.i = hi16; return v.f;
}
__device__ __forceinline__ unsigned short f2bf(float f) {      // RNE
    union { float f; unsigned int i; } v; v.f = f;
    unsigned int i = v.i;
    return (unsigned short)((i + 0x7FFFu + ((i >> 16) & 1u)) >> 16);
}

// ---------------- CSR build ----------------

__global__ void hist_kernel(const int* __restrict__ dst, int* __restrict__ cnt, int nE) {
    int i = blockIdx.x * blockDim.x + threadIdx.x;
    if (i < nE) atomicAdd(&cnt[dst[i]], 1);
}

__global__ void blocksum_kernel(const int* __restrict__ cnt, int* __restrict__ blockSum, int n) {
    int i = blockIdx.x * 256 + threadIdx.x;
    int d = (i < n) ? cnt[i] : 0;
    int lane = threadIdx.x & 63, wid = threadIdx.x >> 6;
    __shared__ int ws[4];
    int v = d;
    for (int off = 32; off; off >>= 1) v += __shfl_down(v, off);
    if (lane == 0) ws[wid] = v;
    __syncthreads();
    if (threadIdx.x == 0) blockSum[blockIdx.x] = ws[0] + ws[1] + ws[2] + ws[3];
}

__global__ void scan_write_kernel(int* __restrict__ cnt, const int* __restrict__ blockSum,
                                  int* __restrict__ row_ptr, float* __restrict__ inv_deg,
                                  int n) {
    const int b = blockIdx.x, tid = threadIdx.x;
    const int lane = tid & 63, wid = tid >> 6;
    __shared__ int wsA[4];
    __shared__ int wsB[4];
    int v = (tid < b) ? blockSum[tid] : 0;
    for (int off = 32; off; off >>= 1) v += __shfl_down(v, off);
    if (lane == 0) wsA[wid] = v;
    int i = b * 256 + tid;
    int d = (i < n) ? cnt[i] : 0;
    int s = d;
    for (int off = 1; off < 64; off <<= 1) {
        int t = __shfl_up(s, off);
        if (lane >= off) s += t;
    }
    if (lane == 63) wsB[wid] = s;
    __syncthreads();
    int blockOff = wsA[0] + wsA[1] + wsA[2] + wsA[3];
    int wOff = 0;
    for (int w = 0; w < wid; ++w) wOff += wsB[w];
    int excl = blockOff + wOff + s - d;
    if (i < n) {
        row_ptr[i] = excl;
        cnt[i]     = excl;
        inv_deg[i] = 1.0f / (float)(d > 1 ? d : 1);
    }
    if (i == n) row_ptr[n] = excl;
}

__global__ void fill_kernel(const int* __restrict__ src, const int* __restrict__ dst,
                            int* __restrict__ cnt, int* __restrict__ col_idx, int nE) {
    int i = blockIdx.x * blockDim.x + threadIdx.x;
    if (i < nE) {
        int pos = atomicAdd(&cnt[dst[i]], 1);
        col_idx[pos] = src[i];
    }
}

// ---------------- conversions ----------------

// x fp32 [n][128] -> combined plane [n][256] (H|L). 4 features/thread.
__global__ void xconv_kernel(const float* __restrict__ x, unsigned short* __restrict__ xc, int n) {
    int i = blockIdx.x * 256 + threadIdx.x;
    if (i >= n * 32) return;
    int node = i >> 5, fb = (i & 31) * 4;
    float4 v = *(const float4*)(x + (size_t)node * NFEAT + fb);
    unsigned short h0 = f2bf(v.x), h1 = f2bf(v.y), h2 = f2bf(v.z), h3 = f2bf(v.w);
    uint2 hw;
    hw.x = (unsigned int)h0 | ((unsigned int)h1 << 16);
    hw.y = (unsigned int)h2 | ((unsigned int)h3 << 16);
    *(uint2*)(xc + (size_t)node * RS + fb) = hw;
    unsigned short l0 = f2bf(v.x - bf2f(h0)), l1 = f2bf(v.y - bf2f(h1));
    unsigned short l2 = f2bf(v.z - bf2f(h2)), l3 = f2bf(v.w - bf2f(h3));
    uint2 lw;
    lw.x = (unsigned int)l0 | ((unsigned int)l1 << 16);
    lw.y = (unsigned int)l2 | ((unsigned int)l3 << 16);
    *(uint2*)(xc + (size_t)node * RS + 128 + fb) = lw;
}

// W -> transposed K-major cat [nout][256]: k<128 from Wl, else Wr; separate H/L planes.
__global__ void wconv_kernel(const float* __restrict__ Wl, const float* __restrict__ Wr,
                             unsigned short* __restrict__ WtH, unsigned short* __restrict__ WtL,
                             int nout) {
    int idx = blockIdx.x * 256 + threadIdx.x;
    if (idx >= nout * 256) return;
    int c = idx >> 8, k = idx & 255;
    float f = (k < 128) ? Wl[k * nout + c] : Wr[(k - 128) * nout + c];
    unsigned short hi = f2bf(f);
    WtH[idx] = hi;
    WtL[idx] = f2bf(f - bf2f(hi));
}

// ---------------- mean aggregation (CSR gather, combined plane) ----------------
// 32 lanes per node; each neighbor row is 512B = 32 lanes x 16B (uint4).
// Lanes 0-15 carry H-halves of features, lanes 16-31 carry L-halves; one
// shfl_down(16) recombines. Unroll-by-4 independent accumulators.
__global__ void agg_kernel(const unsigned short* __restrict__ in,
                           const int* __restrict__ row_ptr, const int* __restrict__ col_idx,
                           const float* __restrict__ inv_deg,
                           unsigned short* __restrict__ agg, int n) {
    int lane = threadIdx.x & 31;
    int node = blockIdx.x * 8 + (threadIdx.x >> 5);
    if (node >= n) return;
    int beg = row_ptr[node], end = row_ptr[node + 1];
    float a0[8] = {0,0,0,0,0,0,0,0}, a1[8] = {0,0,0,0,0,0,0,0};
    float a2[8] = {0,0,0,0,0,0,0,0}, a3[8] = {0,0,0,0,0,0,0,0};
    auto accum = [&](float* a, uint4 v) {
        a[0] += bfhi2f(v.x << 16); a[1] += bfhi2f(v.x & 0xFFFF0000u);
        a[2] += bfhi2f(v.y << 16); a[3] += bfhi2f(v.y & 0xFFFF0000u);
        a[4] += bfhi2f(v.z << 16); a[5] += bfhi2f(v.z & 0xFFFF0000u);
        a[6] += bfhi2f(v.w << 16); a[7] += bfhi2f(v.w & 0xFFFF0000u);
    };
    int e = beg;
    for (; e + 4 <= end; e += 4) {
        int s0 = col_idx[e], s1 = col_idx[e + 1], s2 = col_idx[e + 2], s3 = col_idx[e + 3];
        uint4 v0 = ((const uint4*)(in + (size_t)s0 * RS))[lane];
        uint4 v1 = ((const uint4*)(in + (size_t)s1 * RS))[lane];
        uint4 v2 = ((const uint4*)(in + (size_t)s2 * RS))[lane];
        uint4 v3 = ((const uint4*)(in + (size_t)s3 * RS))[lane];
        accum(a0, v0); accum(a1, v1); accum(a2, v2); accum(a3, v3);
    }
    for (; e < end; ++e) {
        int s = col_idx[e];
        uint4 v = ((const uint4*)(in + (size_t)s * RS))[lane];
        accum(a0, v);
    }
    float s[8];
    #pragma unroll
    for (int j = 0; j < 8; ++j) s[j] = a0[j] + a1[j] + a2[j] + a3[j];
    // combine H (lanes 0-15) with L (lanes 16-31)
    #pragma unroll
    for (int j = 0; j < 8; ++j) {
        float o = __shfl_down(s[j], 16, 32);
        s[j] += o;
    }
    if (lane < 16) {
        float sc = inv_deg[node];
        unsigned short hs[8], ls[8];
        #pragma unroll
        for (int j = 0; j < 8; ++j) {
            float v = s[j] * sc;
            hs[j] = f2bf(v);
            ls[j] = f2bf(v - bf2f(hs[j]));
        }
        uint4 hv, lv;
        hv.x = (unsigned int)hs[0] | ((unsigned int)hs[1] << 16);
        hv.y = (unsigned int)hs[2] | ((unsigned int)hs[3] << 16);
        hv.z = (unsigned int)hs[4] | ((unsigned int)hs[5] << 16);
        hv.w = (unsigned int)hs[6] | ((unsigned int)hs[7] << 16);
        lv.x = (unsigned int)ls[0] | ((unsigned int)ls[1] << 16);
        lv.y = (unsigned int)ls[2] | ((unsigned int)ls[3] << 16);
        lv.z = (unsigned int)ls[4] | ((unsigned int)ls[5] << 16);
        lv.w = (unsigned int)ls[6] | ((unsigned int)ls[7] << 16);
        *(uint4*)(agg + (size_t)node * RS + lane * 8)       = hv;
        *(uint4*)(agg + (size_t)node * RS + 128 + lane * 8) = lv;
    }
}

// ---------------- MFMA GEMM: C = [agg|x] @ [Wl;Wr] + b, split-bf16 ----------------
// B (Wt, K-major [NOUT][256], hi+lo) register-resident: 128 VGPRs. launch_bounds
// (256,2) -> <=256 VGPR cap so the compiler does NOT demote B to reloads (round-4
// lesson: default heuristic allocated 44 VGPRs and killed all ILP).

template<int NOUT, bool RELU, bool FINAL>
__global__ __launch_bounds__(256, 2) void mfma_gemm(
    const unsigned short* __restrict__ aggc, const unsigned short* __restrict__ xc,
    const unsigned short* __restrict__ WtH, const unsigned short* __restrict__ WtL,
    const float* __restrict__ bias,
    float* __restrict__ outF, unsigned short* __restrict__ outC,
    int n)
{
    constexpr int NWC = NOUT / 32;          // waves along cols (4 or 2)
    constexpr int NWR = 4 / NWC;            // waves along rows (1 or 2)
    constexpr int MT  = 32 * NWR;           // nodes per block
    const int wid  = threadIdx.x >> 6;
    const int lane = threadIdx.x & 63;
    const int wc = wid % NWC, wr = wid / NWC;
    const int colBase = wc * 32;
    const int rowBase = blockIdx.x * MT + wr * 32;
    const int lrow = lane & 15;
    const int lk   = (lane >> 4) * 8;

    // B fragments in registers
    bf16x8 bh[2][8], bl[2][8];
    #pragma unroll
    for (int nf = 0; nf < 2; ++nf) {
        const size_t cb = (size_t)(colBase + nf * 16 + lrow) * 256 + lk;
        #pragma unroll
        for (int ks = 0; ks < 8; ++ks) {
            bh[nf][ks] = *(const bf16x8*)(WtH + cb + ks * 32);
            bl[nf][ks] = *(const bf16x8*)(WtL + cb + ks * 32);
        }
    }

    int r0 = rowBase + lrow;       if (r0 > n - 1) r0 = n - 1;
    int r1 = rowBase + 16 + lrow;  if (r1 > n - 1) r1 = n - 1;

    f32x4 acc[2][2];
    #pragma unroll
    for (int mf = 0; mf < 2; ++mf)
        #pragma unroll
        for (int nf = 0; nf < 2; ++nf)
            acc[mf][nf] = (f32x4){0.f, 0.f, 0.f, 0.f};

    #pragma unroll
    for (int ks = 0; ks < 8; ++ks) {
        const unsigned short* S = (ks < 4) ? aggc : xc;
        const int kk = (ks & 3) * 32 + lk;
        bf16x8 a0h = *(const bf16x8*)(S + (size_t)r0 * RS + kk);
        bf16x8 a1h = *(const bf16x8*)(S + (size_t)r1 * RS + kk);
        bf16x8 a0l = *(const bf16x8*)(S + (size_t)r0 * RS + 128 + kk);
        bf16x8 a1l = *(const bf16x8*)(S + (size_t)r1 * RS + 128 + kk);
        #pragma unroll
        for (int nf = 0; nf < 2; ++nf) {
            acc[0][nf] = __builtin_amdgcn_mfma_f32_16x16x32_bf16(a0h, bh[nf][ks], acc[0][nf], 0, 0, 0);
            acc[0][nf] = __builtin_amdgcn_mfma_f32_16x16x32_bf16(a0l, bh[nf][ks], acc[0][nf], 0, 0, 0);
            acc[0][nf] = __builtin_amdgcn_mfma_f32_16x16x32_bf16(a0h, bl[nf][ks], acc[0][nf], 0, 0, 0);
            acc[1][nf] = __builtin_amdgcn_mfma_f32_16x16x32_bf16(a1h, bh[nf][ks], acc[1][nf], 0, 0, 0);
            acc[1][nf] = __builtin_amdgcn_mfma_f32_16x16x32_bf16(a1l, bh[nf][ks], acc[1][nf], 0, 0, 0);
            acc[1][nf] = __builtin_amdgcn_mfma_f32_16x16x32_bf16(a1h, bl[nf][ks], acc[1][nf], 0, 0, 0);
        }
    }

    // epilogue: bias (+ReLU); FINAL -> fp32 out, else -> next-layer combined plane
    #pragma unroll
    for (int mf = 0; mf < 2; ++mf) {
        #pragma unroll
        for (int nf = 0; nf < 2; ++nf) {
            const int c = colBase + nf * 16 + lrow;
            const float bv = bias[c];
            #pragma unroll
            for (int reg = 0; reg < 4; ++reg) {
                const int r = rowBase + mf * 16 + (lane >> 4) * 4 + reg;
                if (r < n) {
                    float h = acc[mf][nf][reg] + bv;
                    if (RELU) h = fmaxf(h, 0.f);
                    if (FINAL) {
                        outF[(size_t)r * NOUT + c] = h;
                    } else {
                        unsigned short hi = f2bf(h);
                        outC[(size_t)r * RS + c]       = hi;
                        outC[(size_t)r * RS + 128 + c] = f2bf(h - bf2f(hi));
                    }
                }
            }
        }
    }
}

extern "C" void kernel_launch(void* const* d_in, const int* in_sizes, int n_in,
                              void* d_out, int out_size, void* d_ws, size_t ws_size,
                              hipStream_t stream) {
    const float* x   = (const float*)d_in[0];
    const int*   ei  = (const int*)d_in[1];
    const float* Wl0 = (const float*)d_in[2];
    const float* Wr0 = (const float*)d_in[3];
    const float* b0  = (const float*)d_in[4];
    const float* Wl1 = (const float*)d_in[5];
    const float* Wr1 = (const float*)d_in[6];
    const float* b1  = (const float*)d_in[7];
    const float* Wl2 = (const float*)d_in[8];
    const float* Wr2 = (const float*)d_in[9];
    const float* b2  = (const float*)d_in[10];

    const int nN = in_sizes[0] / NFEAT;       // 50000
    const int nE = in_sizes[1] / 2;           // 800000
    const int* src = ei;
    const int* dst = ei + nE;

    char* ws = (char*)d_ws;
    size_t off = 0;
    auto take = [&](size_t bytes) { char* p = ws + off; off += (bytes + 255) & ~(size_t)255; return p; };
    int*   cnt      = (int*)  take((size_t)nN * 4);
    int*   row_ptr  = (int*)  take((size_t)(nN + 1) * 4);
    int*   col_idx  = (int*)  take((size_t)nE * 4);
    float* inv_deg  = (float*)take((size_t)nN * 4);
    int*   blockSum = (int*)  take(256 * 4);
    const size_t plane = (size_t)nN * RS * 2;             // combined plane bytes
    unsigned short* aggC = (unsigned short*)take(plane);
    unsigned short* xc0  = (unsigned short*)take(plane);
    unsigned short* xc1  = (unsigned short*)take(plane);
    unsigned short* WtH0 = (unsigned short*)take(128 * 256 * 2);
    unsigned short* WtL0 = (unsigned short*)take(128 * 256 * 2);
    unsigned short* WtH1 = (unsigned short*)take(128 * 256 * 2);
    unsigned short* WtL1 = (unsigned short*)take(128 * 256 * 2);
    unsigned short* WtH2 = (unsigned short*)take(64 * 256 * 2);
    unsigned short* WtL2 = (unsigned short*)take(64 * 256 * 2);
    (void)ws_size; (void)n_in; (void)out_size;

    const int scanBlocks = (nN + 255) / 256;

    // CSR build
    hipMemsetAsync(cnt, 0, (size_t)nN * 4, stream);
    hist_kernel<<<(nE + 255) / 256, 256, 0, stream>>>(dst, cnt, nE);
    blocksum_kernel<<<scanBlocks, 256, 0, stream>>>(cnt, blockSum, nN);
    scan_write_kernel<<<scanBlocks, 256, 0, stream>>>(cnt, blockSum, row_ptr, inv_deg, nN);
    fill_kernel<<<(nE + 255) / 256, 256, 0, stream>>>(src, dst, cnt, col_idx, nE);

    // conversions
    xconv_kernel<<<(nN * 32 + 255) / 256, 256, 0, stream>>>(x, xc0, nN);
    wconv_kernel<<<(128 * 256 + 255) / 256, 256, 0, stream>>>(Wl0, Wr0, WtH0, WtL0, 128);
    wconv_kernel<<<(128 * 256 + 255) / 256, 256, 0, stream>>>(Wl1, Wr1, WtH1, WtL1, 128);
    wconv_kernel<<<(64 * 256 + 255) / 256, 256, 0, stream>>>(Wl2, Wr2, WtH2, WtL2, 64);

    const int aggGrid = (nN + 7) / 8;

    // layer 0: x -> h0
    agg_kernel<<<aggGrid, 256, 0, stream>>>(xc0, row_ptr, col_idx, inv_deg, aggC, nN);
    mfma_gemm<128, true, false><<<(nN + 31) / 32, 256, 0, stream>>>(
        aggC, xc0, WtH0, WtL0, b0, nullptr, xc1, nN);
    // layer 1: h0 -> h1
    agg_kernel<<<aggGrid, 256, 0, stream>>>(xc1, row_ptr, col_idx, inv_deg, aggC, nN);
    mfma_gemm<128, true, false><<<(nN + 31) / 32, 256, 0, stream>>>(
        aggC, xc1, WtH1, WtL1, b1, nullptr, xc0, nN);
    // layer 2: h1 -> out (fp32)
    agg_kernel<<<aggGrid, 256, 0, stream>>>(xc0, row_ptr, col_idx, inv_deg, aggC, nN);
    mfma_gemm<64, false, true><<<(nN + 63) / 64, 256, 0, stream>>>(
        aggC, xc0, WtH2, WtL2, b2, (float*)d_out, nullptr, nN);
}

// Round 6
// 401.217 us; speedup vs baseline: 1.0534x; 1.0534x over previous
//
#include <hip/hip_runtime.h>

#define NFEAT 128
#define RS 256   // combined-plane row stride in shorts: [0,128)=H, [128,256)=L

using bf16x8 = __attribute__((ext_vector_type(8))) short;
using f32x4  = __attribute__((ext_vector_type(4))) float;

__device__ __forceinline__ float bf2f(unsigned short u) {
    union { unsigned int i; float f; } v; v.i = ((unsigned int)u) << 16; return v.f;
}
__device__ __forceinline__ float bfhi2f(unsigned int hi16) {
    union { unsigned int i; float f; } v; v.i = hi16; return v.f;
}
__device__ __forceinline__ unsigned short f2bf(float f) {      // RNE
    union { float f; unsigned int i; } v; v.f = f;
    unsigned int i = v.i;
    return (unsigned short)((i + 0x7FFFu + ((i >> 16) & 1u)) >> 16);
}

// ---------------- CSR build ----------------

__global__ void hist_kernel(const int* __restrict__ dst, int* __restrict__ cnt, int nE) {
    int i = blockIdx.x * blockDim.x + threadIdx.x;
    if (i < nE) atomicAdd(&cnt[dst[i]], 1);
}

__global__ void blocksum_kernel(const int* __restrict__ cnt, int* __restrict__ blockSum, int n) {
    int i = blockIdx.x * 256 + threadIdx.x;
    int d = (i < n) ? cnt[i] : 0;
    int lane = threadIdx.x & 63, wid = threadIdx.x >> 6;
    __shared__ int ws[4];
    int v = d;
    for (int off = 32; off; off >>= 1) v += __shfl_down(v, off);
    if (lane == 0) ws[wid] = v;
    __syncthreads();
    if (threadIdx.x == 0) blockSum[blockIdx.x] = ws[0] + ws[1] + ws[2] + ws[3];
}

__global__ void scan_write_kernel(int* __restrict__ cnt, const int* __restrict__ blockSum,
                                  int* __restrict__ row_ptr, float* __restrict__ inv_deg,
                                  int n) {
    const int b = blockIdx.x, tid = threadIdx.x;
    const int lane = tid & 63, wid = tid >> 6;
    __shared__ int wsA[4];
    __shared__ int wsB[4];
    int v = (tid < b) ? blockSum[tid] : 0;
    for (int off = 32; off; off >>= 1) v += __shfl_down(v, off);
    if (lane == 0) wsA[wid] = v;
    int i = b * 256 + tid;
    int d = (i < n) ? cnt[i] : 0;
    int s = d;
    for (int off = 1; off < 64; off <<= 1) {
        int t = __shfl_up(s, off);
        if (lane >= off) s += t;
    }
    if (lane == 63) wsB[wid] = s;
    __syncthreads();
    int blockOff = wsA[0] + wsA[1] + wsA[2] + wsA[3];
    int wOff = 0;
    for (int w = 0; w < wid; ++w) wOff += wsB[w];
    int excl = blockOff + wOff + s - d;
    if (i < n) {
        row_ptr[i] = excl;
        cnt[i]     = excl;
        inv_deg[i] = 1.0f / (float)(d > 1 ? d : 1);
    }
    if (i == n) row_ptr[n] = excl;
}

__global__ void fill_kernel(const int* __restrict__ src, const int* __restrict__ dst,
                            int* __restrict__ cnt, int* __restrict__ col_idx, int nE) {
    int i = blockIdx.x * blockDim.x + threadIdx.x;
    if (i < nE) {
        int pos = atomicAdd(&cnt[dst[i]], 1);
        col_idx[pos] = src[i];
    }
}

// ---------------- conversions ----------------

__global__ void xconv_kernel(const float* __restrict__ x, unsigned short* __restrict__ xc, int n) {
    int i = blockIdx.x * 256 + threadIdx.x;
    if (i >= n * 32) return;
    int node = i >> 5, fb = (i & 31) * 4;
    float4 v = *(const float4*)(x + (size_t)node * NFEAT + fb);
    unsigned short h0 = f2bf(v.x), h1 = f2bf(v.y), h2 = f2bf(v.z), h3 = f2bf(v.w);
    uint2 hw;
    hw.x = (unsigned int)h0 | ((unsigned int)h1 << 16);
    hw.y = (unsigned int)h2 | ((unsigned int)h3 << 16);
    *(uint2*)(xc + (size_t)node * RS + fb) = hw;
    unsigned short l0 = f2bf(v.x - bf2f(h0)), l1 = f2bf(v.y - bf2f(h1));
    unsigned short l2 = f2bf(v.z - bf2f(h2)), l3 = f2bf(v.w - bf2f(h3));
    uint2 lw;
    lw.x = (unsigned int)l0 | ((unsigned int)l1 << 16);
    lw.y = (unsigned int)l2 | ((unsigned int)l3 << 16);
    *(uint2*)(xc + (size_t)node * RS + 128 + fb) = lw;
}

__global__ void wconv_kernel(const float* __restrict__ Wl, const float* __restrict__ Wr,
                             unsigned short* __restrict__ WtH, unsigned short* __restrict__ WtL,
                             int nout) {
    int idx = blockIdx.x * 256 + threadIdx.x;
    if (idx >= nout * 256) return;
    int c = idx >> 8, k = idx & 255;
    float f = (k < 128) ? Wl[k * nout + c] : Wr[(k - 128) * nout + c];
    unsigned short hi = f2bf(f);
    WtH[idx] = hi;
    WtL[idx] = f2bf(f - bf2f(hi));
}

// ---------------- mean aggregation (CSR gather, combined plane) ----------------
__global__ void agg_kernel(const unsigned short* __restrict__ in,
                           const int* __restrict__ row_ptr, const int* __restrict__ col_idx,
                           const float* __restrict__ inv_deg,
                           unsigned short* __restrict__ agg, int n) {
    int lane = threadIdx.x & 31;
    int node = blockIdx.x * 8 + (threadIdx.x >> 5);
    if (node >= n) return;
    int beg = row_ptr[node], end = row_ptr[node + 1];
    float a0[8] = {0,0,0,0,0,0,0,0}, a1[8] = {0,0,0,0,0,0,0,0};
    float a2[8] = {0,0,0,0,0,0,0,0}, a3[8] = {0,0,0,0,0,0,0,0};
    auto accum = [&](float* a, uint4 v) {
        a[0] += bfhi2f(v.x << 16); a[1] += bfhi2f(v.x & 0xFFFF0000u);
        a[2] += bfhi2f(v.y << 16); a[3] += bfhi2f(v.y & 0xFFFF0000u);
        a[4] += bfhi2f(v.z << 16); a[5] += bfhi2f(v.z & 0xFFFF0000u);
        a[6] += bfhi2f(v.w << 16); a[7] += bfhi2f(v.w & 0xFFFF0000u);
    };
    int e = beg;
    for (; e + 4 <= end; e += 4) {
        int s0 = col_idx[e], s1 = col_idx[e + 1], s2 = col_idx[e + 2], s3 = col_idx[e + 3];
        uint4 v0 = ((const uint4*)(in + (size_t)s0 * RS))[lane];
        uint4 v1 = ((const uint4*)(in + (size_t)s1 * RS))[lane];
        uint4 v2 = ((const uint4*)(in + (size_t)s2 * RS))[lane];
        uint4 v3 = ((const uint4*)(in + (size_t)s3 * RS))[lane];
        accum(a0, v0); accum(a1, v1); accum(a2, v2); accum(a3, v3);
    }
    for (; e < end; ++e) {
        int s = col_idx[e];
        uint4 v = ((const uint4*)(in + (size_t)s * RS))[lane];
        accum(a0, v);
    }
    float s[8];
    #pragma unroll
    for (int j = 0; j < 8; ++j) s[j] = a0[j] + a1[j] + a2[j] + a3[j];
    #pragma unroll
    for (int j = 0; j < 8; ++j) {
        float o = __shfl_down(s[j], 16, 32);
        s[j] += o;
    }
    if (lane < 16) {
        float sc = inv_deg[node];
        unsigned short hs[8], ls[8];
        #pragma unroll
        for (int j = 0; j < 8; ++j) {
            float v = s[j] * sc;
            hs[j] = f2bf(v);
            ls[j] = f2bf(v - bf2f(hs[j]));
        }
        uint4 hv, lv;
        hv.x = (unsigned int)hs[0] | ((unsigned int)hs[1] << 16);
        hv.y = (unsigned int)hs[2] | ((unsigned int)hs[3] << 16);
        hv.z = (unsigned int)hs[4] | ((unsigned int)hs[5] << 16);
        hv.w = (unsigned int)hs[6] | ((unsigned int)hs[7] << 16);
        lv.x = (unsigned int)ls[0] | ((unsigned int)ls[1] << 16);
        lv.y = (unsigned int)ls[2] | ((unsigned int)ls[3] << 16);
        lv.z = (unsigned int)ls[4] | ((unsigned int)ls[5] << 16);
        lv.w = (unsigned int)ls[6] | ((unsigned int)ls[7] << 16);
        *(uint4*)(agg + (size_t)node * RS + lane * 8)       = hv;
        *(uint4*)(agg + (size_t)node * RS + 128 + lane * 8) = lv;
    }
}

// ---------------- MFMA GEMM: C = [agg|x] @ [Wl;Wr] + b, split-bf16 ----------------
// Round-6 structure: B fragments loaded ONCE, then sched_barrier(0) pins them
// pre-K-loop (round-5 lesson: scheduler sank loop-invariant loads -> VGPR 36,
// reload-per-use, MfmaUtil 6%). RPT row-tiles per block amortize the B load;
// A loads for kstep ks+1 issue before MFMAs of ks (software pipeline).

template<int NOUT, bool RELU, bool FINAL, int RPT>
__global__ __launch_bounds__(256, 2) void mfma_gemm(
    const unsigned short* __restrict__ aggc, const unsigned short* __restrict__ xc,
    const unsigned short* __restrict__ WtH, const unsigned short* __restrict__ WtL,
    const float* __restrict__ bias,
    float* __restrict__ outF, unsigned short* __restrict__ outC,
    int n)
{
    constexpr int NWC = NOUT / 32;          // waves along cols (4 or 2)
    constexpr int NWR = 4 / NWC;            // waves along rows (1 or 2)
    constexpr int MT  = 32 * NWR;           // nodes per tile
    const int wid  = threadIdx.x >> 6;
    const int lane = threadIdx.x & 63;
    const int wc = wid % NWC, wr = wid / NWC;
    const int colBase = wc * 32;
    const int lrow = lane & 15;
    const int lk   = (lane >> 4) * 8;

    // B fragments in registers (128 VGPRs), pinned by sched_barrier below.
    bf16x8 bh[2][8], bl[2][8];
    #pragma unroll
    for (int nf = 0; nf < 2; ++nf) {
        const size_t cb = (size_t)(colBase + nf * 16 + lrow) * 256 + lk;
        #pragma unroll
        for (int ks = 0; ks < 8; ++ks) {
            bh[nf][ks] = *(const bf16x8*)(WtH + cb + ks * 32);
            bl[nf][ks] = *(const bf16x8*)(WtL + cb + ks * 32);
        }
    }
    __builtin_amdgcn_sched_barrier(0);      // nothing crosses: B loads stay hoisted

    #pragma unroll
    for (int t = 0; t < RPT; ++t) {
        const int rowBase = (blockIdx.x * RPT + t) * MT + wr * 32;
        int r0 = rowBase + lrow;       if (r0 > n - 1) r0 = n - 1;
        int r1 = rowBase + 16 + lrow;  if (r1 > n - 1) r1 = n - 1;

        f32x4 acc[2][2];
        #pragma unroll
        for (int mf = 0; mf < 2; ++mf)
            #pragma unroll
            for (int nf = 0; nf < 2; ++nf)
                acc[mf][nf] = (f32x4){0.f, 0.f, 0.f, 0.f};

        // prefetch kstep 0
        bf16x8 a0h, a1h, a0l, a1l;
        {
            const unsigned short* S = aggc;
            a0h = *(const bf16x8*)(S + (size_t)r0 * RS + lk);
            a1h = *(const bf16x8*)(S + (size_t)r1 * RS + lk);
            a0l = *(const bf16x8*)(S + (size_t)r0 * RS + 128 + lk);
            a1l = *(const bf16x8*)(S + (size_t)r1 * RS + 128 + lk);
        }
        #pragma unroll
        for (int ks = 0; ks < 8; ++ks) {
            bf16x8 c0h = a0h, c1h = a1h, c0l = a0l, c1l = a1l;
            if (ks < 7) {                   // issue next kstep's loads first
                const int ksn = ks + 1;
                const unsigned short* S = (ksn < 4) ? aggc : xc;
                const int kk = (ksn & 3) * 32 + lk;
                a0h = *(const bf16x8*)(S + (size_t)r0 * RS + kk);
                a1h = *(const bf16x8*)(S + (size_t)r1 * RS + kk);
                a0l = *(const bf16x8*)(S + (size_t)r0 * RS + 128 + kk);
                a1l = *(const bf16x8*)(S + (size_t)r1 * RS + 128 + kk);
            }
            #pragma unroll
            for (int nf = 0; nf < 2; ++nf) {
                acc[0][nf] = __builtin_amdgcn_mfma_f32_16x16x32_bf16(c0h, bh[nf][ks], acc[0][nf], 0, 0, 0);
                acc[0][nf] = __builtin_amdgcn_mfma_f32_16x16x32_bf16(c0l, bh[nf][ks], acc[0][nf], 0, 0, 0);
                acc[0][nf] = __builtin_amdgcn_mfma_f32_16x16x32_bf16(c0h, bl[nf][ks], acc[0][nf], 0, 0, 0);
                acc[1][nf] = __builtin_amdgcn_mfma_f32_16x16x32_bf16(c1h, bh[nf][ks], acc[1][nf], 0, 0, 0);
                acc[1][nf] = __builtin_amdgcn_mfma_f32_16x16x32_bf16(c1l, bh[nf][ks], acc[1][nf], 0, 0, 0);
                acc[1][nf] = __builtin_amdgcn_mfma_f32_16x16x32_bf16(c1h, bl[nf][ks], acc[1][nf], 0, 0, 0);
            }
        }

        // epilogue: bias (+ReLU); FINAL -> fp32 out, else -> combined plane
        #pragma unroll
        for (int mf = 0; mf < 2; ++mf) {
            #pragma unroll
            for (int nf = 0; nf < 2; ++nf) {
                const int c = colBase + nf * 16 + lrow;
                const float bv = bias[c];
                #pragma unroll
                for (int reg = 0; reg < 4; ++reg) {
                    const int r = rowBase + mf * 16 + (lane >> 4) * 4 + reg;
                    if (r < n) {
                        float h = acc[mf][nf][reg] + bv;
                        if (RELU) h = fmaxf(h, 0.f);
                        if (FINAL) {
                            outF[(size_t)r * NOUT + c] = h;
                        } else {
                            unsigned short hi = f2bf(h);
                            outC[(size_t)r * RS + c]       = hi;
                            outC[(size_t)r * RS + 128 + c] = f2bf(h - bf2f(hi));
                        }
                    }
                }
            }
        }
    }
}

extern "C" void kernel_launch(void* const* d_in, const int* in_sizes, int n_in,
                              void* d_out, int out_size, void* d_ws, size_t ws_size,
                              hipStream_t stream) {
    const float* x   = (const float*)d_in[0];
    const int*   ei  = (const int*)d_in[1];
    const float* Wl0 = (const float*)d_in[2];
    const float* Wr0 = (const float*)d_in[3];
    const float* b0  = (const float*)d_in[4];
    const float* Wl1 = (const float*)d_in[5];
    const float* Wr1 = (const float*)d_in[6];
    const float* b1  = (const float*)d_in[7];
    const float* Wl2 = (const float*)d_in[8];
    const float* Wr2 = (const float*)d_in[9];
    const float* b2  = (const float*)d_in[10];

    const int nN = in_sizes[0] / NFEAT;       // 50000
    const int nE = in_sizes[1] / 2;           // 800000
    const int* src = ei;
    const int* dst = ei + nE;

    char* ws = (char*)d_ws;
    size_t off = 0;
    auto take = [&](size_t bytes) { char* p = ws + off; off += (bytes + 255) & ~(size_t)255; return p; };
    int*   cnt      = (int*)  take((size_t)nN * 4);
    int*   row_ptr  = (int*)  take((size_t)(nN + 1) * 4);
    int*   col_idx  = (int*)  take((size_t)nE * 4);
    float* inv_deg  = (float*)take((size_t)nN * 4);
    int*   blockSum = (int*)  take(256 * 4);
    const size_t plane = (size_t)nN * RS * 2;             // combined plane bytes
    unsigned short* aggC = (unsigned short*)take(plane);
    unsigned short* xc0  = (unsigned short*)take(plane);
    unsigned short* xc1  = (unsigned short*)take(plane);
    unsigned short* WtH0 = (unsigned short*)take(128 * 256 * 2);
    unsigned short* WtL0 = (unsigned short*)take(128 * 256 * 2);
    unsigned short* WtH1 = (unsigned short*)take(128 * 256 * 2);
    unsigned short* WtL1 = (unsigned short*)take(128 * 256 * 2);
    unsigned short* WtH2 = (unsigned short*)take(64 * 256 * 2);
    unsigned short* WtL2 = (unsigned short*)take(64 * 256 * 2);
    (void)ws_size; (void)n_in; (void)out_size;

    const int scanBlocks = (nN + 255) / 256;

    // CSR build
    hipMemsetAsync(cnt, 0, (size_t)nN * 4, stream);
    hist_kernel<<<(nE + 255) / 256, 256, 0, stream>>>(dst, cnt, nE);
    blocksum_kernel<<<scanBlocks, 256, 0, stream>>>(cnt, blockSum, nN);
    scan_write_kernel<<<scanBlocks, 256, 0, stream>>>(cnt, blockSum, row_ptr, inv_deg, nN);
    fill_kernel<<<(nE + 255) / 256, 256, 0, stream>>>(src, dst, cnt, col_idx, nE);

    // conversions
    xconv_kernel<<<(nN * 32 + 255) / 256, 256, 0, stream>>>(x, xc0, nN);
    wconv_kernel<<<(128 * 256 + 255) / 256, 256, 0, stream>>>(Wl0, Wr0, WtH0, WtL0, 128);
    wconv_kernel<<<(128 * 256 + 255) / 256, 256, 0, stream>>>(Wl1, Wr1, WtH1, WtL1, 128);
    wconv_kernel<<<(64 * 256 + 255) / 256, 256, 0, stream>>>(Wl2, Wr2, WtH2, WtL2, 64);

    const int aggGrid = (nN + 7) / 8;
    const int g01 = (nN + 63) / 64;           // MT=32, RPT=2
    const int g2  = (nN + 127) / 128;         // MT=64, RPT=2

    // layer 0: x -> h0
    agg_kernel<<<aggGrid, 256, 0, stream>>>(xc0, row_ptr, col_idx, inv_deg, aggC, nN);
    mfma_gemm<128, true, false, 2><<<g01, 256, 0, stream>>>(
        aggC, xc0, WtH0, WtL0, b0, nullptr, xc1, nN);
    // layer 1: h0 -> h1
    agg_kernel<<<aggGrid, 256, 0, stream>>>(xc1, row_ptr, col_idx, inv_deg, aggC, nN);
    mfma_gemm<128, true, false, 2><<<g01, 256, 0, stream>>>(
        aggC, xc1, WtH1, WtL1, b1, nullptr, xc0, nN);
    // layer 2: h1 -> out (fp32)
    agg_kernel<<<aggGrid, 256, 0, stream>>>(xc0, row_ptr, col_idx, inv_deg, aggC, nN);
    mfma_gemm<64, false, true, 2><<<g2, 256, 0, stream>>>(
        aggC, xc0, WtH2, WtL2, b2, (float*)d_out, nullptr, nN);
}

// Round 7
// 346.131 us; speedup vs baseline: 1.2211x; 1.1591x over previous
//
#include <hip/hip_runtime.h>

#define NFEAT 128
#define RS 256   // combined-plane row stride in shorts: [0,128)=H, [128,256)=L

using bf16x8 = __attribute__((ext_vector_type(8))) short;
using f32x4  = __attribute__((ext_vector_type(4))) float;

__device__ __forceinline__ float bf2f(unsigned short u) {
    union { unsigned int i; float f; } v; v.i = ((unsigned int)u) << 16; return v.f;
}
__device__ __forceinline__ float bfhi2f(unsigned int hi16) {
    union { unsigned int i; float f; } v; v.i = hi16; return v.f;
}
__device__ __forceinline__ unsigned short f2bf(float f) {      // RNE
    union { float f; unsigned int i; } v; v.f = f;
    unsigned int i = v.i;
    return (unsigned short)((i + 0x7FFFu + ((i >> 16) & 1u)) >> 16);
}

// ---------------- CSR build ----------------

__global__ void hist_kernel(const int* __restrict__ dst, int* __restrict__ cnt, int nE) {
    int i = blockIdx.x * blockDim.x + threadIdx.x;
    if (i < nE) atomicAdd(&cnt[dst[i]], 1);
}

__global__ void blocksum_kernel(const int* __restrict__ cnt, int* __restrict__ blockSum, int n) {
    int i = blockIdx.x * 256 + threadIdx.x;
    int d = (i < n) ? cnt[i] : 0;
    int lane = threadIdx.x & 63, wid = threadIdx.x >> 6;
    __shared__ int ws[4];
    int v = d;
    for (int off = 32; off; off >>= 1) v += __shfl_down(v, off);
    if (lane == 0) ws[wid] = v;
    __syncthreads();
    if (threadIdx.x == 0) blockSum[blockIdx.x] = ws[0] + ws[1] + ws[2] + ws[3];
}

__global__ void scan_write_kernel(int* __restrict__ cnt, const int* __restrict__ blockSum,
                                  int* __restrict__ row_ptr, float* __restrict__ inv_deg,
                                  int n) {
    const int b = blockIdx.x, tid = threadIdx.x;
    const int lane = tid & 63, wid = tid >> 6;
    __shared__ int wsA[4];
    __shared__ int wsB[4];
    int v = (tid < b) ? blockSum[tid] : 0;
    for (int off = 32; off; off >>= 1) v += __shfl_down(v, off);
    if (lane == 0) wsA[wid] = v;
    int i = b * 256 + tid;
    int d = (i < n) ? cnt[i] : 0;
    int s = d;
    for (int off = 1; off < 64; off <<= 1) {
        int t = __shfl_up(s, off);
        if (lane >= off) s += t;
    }
    if (lane == 63) wsB[wid] = s;
    __syncthreads();
    int blockOff = wsA[0] + wsA[1] + wsA[2] + wsA[3];
    int wOff = 0;
    for (int w = 0; w < wid; ++w) wOff += wsB[w];
    int excl = blockOff + wOff + s - d;
    if (i < n) {
        row_ptr[i] = excl;
        cnt[i]     = excl;
        inv_deg[i] = 1.0f / (float)(d > 1 ? d : 1);
    }
    if (i == n) row_ptr[n] = excl;
}

__global__ void fill_kernel(const int* __restrict__ src, const int* __restrict__ dst,
                            int* __restrict__ cnt, int* __restrict__ col_idx, int nE) {
    int i = blockIdx.x * blockDim.x + threadIdx.x;
    if (i < nE) {
        int pos = atomicAdd(&cnt[dst[i]], 1);
        col_idx[pos] = src[i];
    }
}

// ---------------- conversions ----------------

__global__ void xconv_kernel(const float* __restrict__ x, unsigned short* __restrict__ xc, int n) {
    int i = blockIdx.x * 256 + threadIdx.x;
    if (i >= n * 32) return;
    int node = i >> 5, fb = (i & 31) * 4;
    float4 v = *(const float4*)(x + (size_t)node * NFEAT + fb);
    unsigned short h0 = f2bf(v.x), h1 = f2bf(v.y), h2 = f2bf(v.z), h3 = f2bf(v.w);
    uint2 hw;
    hw.x = (unsigned int)h0 | ((unsigned int)h1 << 16);
    hw.y = (unsigned int)h2 | ((unsigned int)h3 << 16);
    *(uint2*)(xc + (size_t)node * RS + fb) = hw;
    unsigned short l0 = f2bf(v.x - bf2f(h0)), l1 = f2bf(v.y - bf2f(h1));
    unsigned short l2 = f2bf(v.z - bf2f(h2)), l3 = f2bf(v.w - bf2f(h3));
    uint2 lw;
    lw.x = (unsigned int)l0 | ((unsigned int)l1 << 16);
    lw.y = (unsigned int)l2 | ((unsigned int)l3 << 16);
    *(uint2*)(xc + (size_t)node * RS + 128 + fb) = lw;
}

__global__ void wconv_kernel(const float* __restrict__ Wl, const float* __restrict__ Wr,
                             unsigned short* __restrict__ WtH, unsigned short* __restrict__ WtL,
                             int nout) {
    int idx = blockIdx.x * 256 + threadIdx.x;
    if (idx >= nout * 256) return;
    int c = idx >> 8, k = idx & 255;
    float f = (k < 128) ? Wl[k * nout + c] : Wr[(k - 128) * nout + c];
    unsigned short hi = f2bf(f);
    WtH[idx] = hi;
    WtL[idx] = f2bf(f - bf2f(hi));
}

// ---------------- mean aggregation (CSR gather, H-plane only) ----------------
// Round-7: gather reads only the H half of each neighbor row (256 B instead of
// 512 B) -- the L plane contributes <=2^-9 relative to the mean, far inside the
// absmax budget. 32 lanes/node, uint2 (4 features)/lane, unroll 8 keeps 8 loads
// in flight. Output mean still computed fp32 and written as full H+L.
__global__ void agg_kernel(const unsigned short* __restrict__ in,
                           const int* __restrict__ row_ptr, const int* __restrict__ col_idx,
                           const float* __restrict__ inv_deg,
                           unsigned short* __restrict__ agg, int n) {
    int lane = threadIdx.x & 31;
    int node = blockIdx.x * 8 + (threadIdx.x >> 5);
    if (node >= n) return;
    int beg = row_ptr[node], end = row_ptr[node + 1];
    float a[8][4];
    #pragma unroll
    for (int u = 0; u < 8; ++u)
        #pragma unroll
        for (int j = 0; j < 4; ++j) a[u][j] = 0.f;
    auto acc4 = [&](float* a4, uint2 v) {
        a4[0] += bfhi2f(v.x << 16); a4[1] += bfhi2f(v.x & 0xFFFF0000u);
        a4[2] += bfhi2f(v.y << 16); a4[3] += bfhi2f(v.y & 0xFFFF0000u);
    };
    int e = beg;
    for (; e + 8 <= end; e += 8) {
        uint2 v[8];
        #pragma unroll
        for (int u = 0; u < 8; ++u) {
            int s = col_idx[e + u];
            v[u] = ((const uint2*)(in + (size_t)s * RS))[lane];
        }
        #pragma unroll
        for (int u = 0; u < 8; ++u) acc4(a[u], v[u]);
    }
    for (; e < end; ++e) {
        int s = col_idx[e];
        uint2 v = ((const uint2*)(in + (size_t)s * RS))[lane];
        acc4(a[0], v);
    }
    float s4[4];
    #pragma unroll
    for (int j = 0; j < 4; ++j)
        s4[j] = ((a[0][j] + a[1][j]) + (a[2][j] + a[3][j]))
              + ((a[4][j] + a[5][j]) + (a[6][j] + a[7][j]));
    float sc = inv_deg[node];
    unsigned short hs[4], ls[4];
    #pragma unroll
    for (int j = 0; j < 4; ++j) {
        float v = s4[j] * sc;
        hs[j] = f2bf(v);
        ls[j] = f2bf(v - bf2f(hs[j]));
    }
    uint2 hv, lv;
    hv.x = (unsigned int)hs[0] | ((unsigned int)hs[1] << 16);
    hv.y = (unsigned int)hs[2] | ((unsigned int)hs[3] << 16);
    lv.x = (unsigned int)ls[0] | ((unsigned int)ls[1] << 16);
    lv.y = (unsigned int)ls[2] | ((unsigned int)ls[3] << 16);
    *(uint2*)(agg + (size_t)node * RS + lane * 4)       = hv;
    *(uint2*)(agg + (size_t)node * RS + 128 + lane * 4) = lv;
}

// ---------------- MFMA GEMM: C = [agg|x] @ [Wl;Wr] + b, split-bf16 ----------------
// B fragments loaded ONCE, then sched_barrier(0) pins them pre-K-loop (round-5
// lesson: scheduler sank loop-invariant loads -> reload-per-use, MfmaUtil 6%).
// RPT row-tiles per block amortize the B load; A loads for kstep ks+1 issue
// before MFMAs of ks.

template<int NOUT, bool RELU, bool FINAL, int RPT>
__global__ __launch_bounds__(256, 2) void mfma_gemm(
    const unsigned short* __restrict__ aggc, const unsigned short* __restrict__ xc,
    const unsigned short* __restrict__ WtH, const unsigned short* __restrict__ WtL,
    const float* __restrict__ bias,
    float* __restrict__ outF, unsigned short* __restrict__ outC,
    int n)
{
    constexpr int NWC = NOUT / 32;
    constexpr int NWR = 4 / NWC;
    constexpr int MT  = 32 * NWR;
    const int wid  = threadIdx.x >> 6;
    const int lane = threadIdx.x & 63;
    const int wc = wid % NWC, wr = wid / NWC;
    const int colBase = wc * 32;
    const int lrow = lane & 15;
    const int lk   = (lane >> 4) * 8;

    bf16x8 bh[2][8], bl[2][8];
    #pragma unroll
    for (int nf = 0; nf < 2; ++nf) {
        const size_t cb = (size_t)(colBase + nf * 16 + lrow) * 256 + lk;
        #pragma unroll
        for (int ks = 0; ks < 8; ++ks) {
            bh[nf][ks] = *(const bf16x8*)(WtH + cb + ks * 32);
            bl[nf][ks] = *(const bf16x8*)(WtL + cb + ks * 32);
        }
    }
    __builtin_amdgcn_sched_barrier(0);      // B loads stay hoisted

    #pragma unroll
    for (int t = 0; t < RPT; ++t) {
        const int rowBase = (blockIdx.x * RPT + t) * MT + wr * 32;
        int r0 = rowBase + lrow;       if (r0 > n - 1) r0 = n - 1;
        int r1 = rowBase + 16 + lrow;  if (r1 > n - 1) r1 = n - 1;

        f32x4 acc[2][2];
        #pragma unroll
        for (int mf = 0; mf < 2; ++mf)
            #pragma unroll
            for (int nf = 0; nf < 2; ++nf)
                acc[mf][nf] = (f32x4){0.f, 0.f, 0.f, 0.f};

        bf16x8 a0h, a1h, a0l, a1l;
        {
            const unsigned short* S = aggc;
            a0h = *(const bf16x8*)(S + (size_t)r0 * RS + lk);
            a1h = *(const bf16x8*)(S + (size_t)r1 * RS + lk);
            a0l = *(const bf16x8*)(S + (size_t)r0 * RS + 128 + lk);
            a1l = *(const bf16x8*)(S + (size_t)r1 * RS + 128 + lk);
        }
        #pragma unroll
        for (int ks = 0; ks < 8; ++ks) {
            bf16x8 c0h = a0h, c1h = a1h, c0l = a0l, c1l = a1l;
            if (ks < 7) {
                const int ksn = ks + 1;
                const unsigned short* S = (ksn < 4) ? aggc : xc;
                const int kk = (ksn & 3) * 32 + lk;
                a0h = *(const bf16x8*)(S + (size_t)r0 * RS + kk);
                a1h = *(const bf16x8*)(S + (size_t)r1 * RS + kk);
                a0l = *(const bf16x8*)(S + (size_t)r0 * RS + 128 + kk);
                a1l = *(const bf16x8*)(S + (size_t)r1 * RS + 128 + kk);
            }
            #pragma unroll
            for (int nf = 0; nf < 2; ++nf) {
                acc[0][nf] = __builtin_amdgcn_mfma_f32_16x16x32_bf16(c0h, bh[nf][ks], acc[0][nf], 0, 0, 0);
                acc[0][nf] = __builtin_amdgcn_mfma_f32_16x16x32_bf16(c0l, bh[nf][ks], acc[0][nf], 0, 0, 0);
                acc[0][nf] = __builtin_amdgcn_mfma_f32_16x16x32_bf16(c0h, bl[nf][ks], acc[0][nf], 0, 0, 0);
                acc[1][nf] = __builtin_amdgcn_mfma_f32_16x16x32_bf16(c1h, bh[nf][ks], acc[1][nf], 0, 0, 0);
                acc[1][nf] = __builtin_amdgcn_mfma_f32_16x16x32_bf16(c1l, bh[nf][ks], acc[1][nf], 0, 0, 0);
                acc[1][nf] = __builtin_amdgcn_mfma_f32_16x16x32_bf16(c1h, bl[nf][ks], acc[1][nf], 0, 0, 0);
            }
        }

        #pragma unroll
        for (int mf = 0; mf < 2; ++mf) {
            #pragma unroll
            for (int nf = 0; nf < 2; ++nf) {
                const int c = colBase + nf * 16 + lrow;
                const float bv = bias[c];
                #pragma unroll
                for (int reg = 0; reg < 4; ++reg) {
                    const int r = rowBase + mf * 16 + (lane >> 4) * 4 + reg;
                    if (r < n) {
                        float h = acc[mf][nf][reg] + bv;
                        if (RELU) h = fmaxf(h, 0.f);
                        if (FINAL) {
                            outF[(size_t)r * NOUT + c] = h;
                        } else {
                            unsigned short hi = f2bf(h);
                            outC[(size_t)r * RS + c]       = hi;
                            outC[(size_t)r * RS + 128 + c] = f2bf(h - bf2f(hi));
                        }
                    }
                }
            }
        }
    }
}

extern "C" void kernel_launch(void* const* d_in, const int* in_sizes, int n_in,
                              void* d_out, int out_size, void* d_ws, size_t ws_size,
                              hipStream_t stream) {
    const float* x   = (const float*)d_in[0];
    const int*   ei  = (const int*)d_in[1];
    const float* Wl0 = (const float*)d_in[2];
    const float* Wr0 = (const float*)d_in[3];
    const float* b0  = (const float*)d_in[4];
    const float* Wl1 = (const float*)d_in[5];
    const float* Wr1 = (const float*)d_in[6];
    const float* b1  = (const float*)d_in[7];
    const float* Wl2 = (const float*)d_in[8];
    const float* Wr2 = (const float*)d_in[9];
    const float* b2  = (const float*)d_in[10];

    const int nN = in_sizes[0] / NFEAT;       // 50000
    const int nE = in_sizes[1] / 2;           // 800000
    const int* src = ei;
    const int* dst = ei + nE;

    char* ws = (char*)d_ws;
    size_t off = 0;
    auto take = [&](size_t bytes) { char* p = ws + off; off += (bytes + 255) & ~(size_t)255; return p; };
    int*   cnt      = (int*)  take((size_t)nN * 4);
    int*   row_ptr  = (int*)  take((size_t)(nN + 1) * 4);
    int*   col_idx  = (int*)  take((size_t)nE * 4);
    float* inv_deg  = (float*)take((size_t)nN * 4);
    int*   blockSum = (int*)  take(256 * 4);
    const size_t plane = (size_t)nN * RS * 2;
    unsigned short* aggC = (unsigned short*)take(plane);
    unsigned short* xc0  = (unsigned short*)take(plane);
    unsigned short* xc1  = (unsigned short*)take(plane);
    unsigned short* WtH0 = (unsigned short*)take(128 * 256 * 2);
    unsigned short* WtL0 = (unsigned short*)take(128 * 256 * 2);
    unsigned short* WtH1 = (unsigned short*)take(128 * 256 * 2);
    unsigned short* WtL1 = (unsigned short*)take(128 * 256 * 2);
    unsigned short* WtH2 = (unsigned short*)take(64 * 256 * 2);
    unsigned short* WtL2 = (unsigned short*)take(64 * 256 * 2);
    (void)ws_size; (void)n_in; (void)out_size;

    const int scanBlocks = (nN + 255) / 256;

    // CSR build
    hipMemsetAsync(cnt, 0, (size_t)nN * 4, stream);
    hist_kernel<<<(nE + 255) / 256, 256, 0, stream>>>(dst, cnt, nE);
    blocksum_kernel<<<scanBlocks, 256, 0, stream>>>(cnt, blockSum, nN);
    scan_write_kernel<<<scanBlocks, 256, 0, stream>>>(cnt, blockSum, row_ptr, inv_deg, nN);
    fill_kernel<<<(nE + 255) / 256, 256, 0, stream>>>(src, dst, cnt, col_idx, nE);

    // conversions
    xconv_kernel<<<(nN * 32 + 255) / 256, 256, 0, stream>>>(x, xc0, nN);
    wconv_kernel<<<(128 * 256 + 255) / 256, 256, 0, stream>>>(Wl0, Wr0, WtH0, WtL0, 128);
    wconv_kernel<<<(128 * 256 + 255) / 256, 256, 0, stream>>>(Wl1, Wr1, WtH1, WtL1, 128);
    wconv_kernel<<<(64 * 256 + 255) / 256, 256, 0, stream>>>(Wl2, Wr2, WtH2, WtL2, 64);

    const int aggGrid = (nN + 7) / 8;
    const int g01 = (nN + 63) / 64;           // MT=32, RPT=2
    const int g2  = (nN + 127) / 128;         // MT=64, RPT=2

    // layer 0: x -> h0
    agg_kernel<<<aggGrid, 256, 0, stream>>>(xc0, row_ptr, col_idx, inv_deg, aggC, nN);
    mfma_gemm<128, true, false, 2><<<g01, 256, 0, stream>>>(
        aggC, xc0, WtH0, WtL0, b0, nullptr, xc1, nN);
    // layer 1: h0 -> h1
    agg_kernel<<<aggGrid, 256, 0, stream>>>(xc1, row_ptr, col_idx, inv_deg, aggC, nN);
    mfma_gemm<128, true, false, 2><<<g01, 256, 0, stream>>>(
        aggC, xc1, WtH1, WtL1, b1, nullptr, xc0, nN);
    // layer 2: h1 -> out (fp32)
    agg_kernel<<<aggGrid, 256, 0, stream>>>(xc0, row_ptr, col_idx, inv_deg, aggC, nN);
    mfma_gemm<64, false, true, 2><<<g2, 256, 0, stream>>>(
        aggC, xc0, WtH2, WtL2, b2, (float*)d_out, nullptr, nN);
}

// Round 8
// 316.968 us; speedup vs baseline: 1.3334x; 1.0920x over previous
//
#include <hip/hip_runtime.h>

#define NFEAT 128
#define RS 256   // combined-plane row stride in shorts: [0,128)=H, [128,256)=L

using bf16x8 = __attribute__((ext_vector_type(8))) short;
using f32x4  = __attribute__((ext_vector_type(4))) float;

__device__ __forceinline__ float bf2f(unsigned short u) {
    union { unsigned int i; float f; } v; v.i = ((unsigned int)u) << 16; return v.f;
}
__device__ __forceinline__ float bfhi2f(unsigned int hi16) {
    union { unsigned int i; float f; } v; v.i = hi16; return v.f;
}
__device__ __forceinline__ unsigned short f2bf(float f) {      // RNE
    union { float f; unsigned int i; } v; v.f = f;
    unsigned int i = v.i;
    return (unsigned short)((i + 0x7FFFu + ((i >> 16) & 1u)) >> 16);
}

// ---------------- CSR build ----------------

__global__ void hist_kernel(const int* __restrict__ dst, int* __restrict__ cnt, int nE) {
    int i = blockIdx.x * blockDim.x + threadIdx.x;
    if (i < nE) atomicAdd(&cnt[dst[i]], 1);
}

__global__ void blocksum_kernel(const int* __restrict__ cnt, int* __restrict__ blockSum, int n) {
    int i = blockIdx.x * 256 + threadIdx.x;
    int d = (i < n) ? cnt[i] : 0;
    int lane = threadIdx.x & 63, wid = threadIdx.x >> 6;
    __shared__ int ws[4];
    int v = d;
    for (int off = 32; off; off >>= 1) v += __shfl_down(v, off);
    if (lane == 0) ws[wid] = v;
    __syncthreads();
    if (threadIdx.x == 0) blockSum[blockIdx.x] = ws[0] + ws[1] + ws[2] + ws[3];
}

__global__ void scan_write_kernel(int* __restrict__ cnt, const int* __restrict__ blockSum,
                                  int* __restrict__ row_ptr, float* __restrict__ inv_deg,
                                  int n) {
    const int b = blockIdx.x, tid = threadIdx.x;
    const int lane = tid & 63, wid = tid >> 6;
    __shared__ int wsA[4];
    __shared__ int wsB[4];
    int v = (tid < b) ? blockSum[tid] : 0;
    for (int off = 32; off; off >>= 1) v += __shfl_down(v, off);
    if (lane == 0) wsA[wid] = v;
    int i = b * 256 + tid;
    int d = (i < n) ? cnt[i] : 0;
    int s = d;
    for (int off = 1; off < 64; off <<= 1) {
        int t = __shfl_up(s, off);
        if (lane >= off) s += t;
    }
    if (lane == 63) wsB[wid] = s;
    __syncthreads();
    int blockOff = wsA[0] + wsA[1] + wsA[2] + wsA[3];
    int wOff = 0;
    for (int w = 0; w < wid; ++w) wOff += wsB[w];
    int excl = blockOff + wOff + s - d;
    if (i < n) {
        row_ptr[i] = excl;
        cnt[i]     = excl;
        inv_deg[i] = 1.0f / (float)(d > 1 ? d : 1);
    }
    if (i == n) row_ptr[n] = excl;
}

__global__ void fill_kernel(const int* __restrict__ src, const int* __restrict__ dst,
                            int* __restrict__ cnt, int* __restrict__ col_idx, int nE) {
    int i = blockIdx.x * blockDim.x + threadIdx.x;
    if (i < nE) {
        int pos = atomicAdd(&cnt[dst[i]], 1);
        col_idx[pos] = src[i];
    }
}

// ---------------- conversions ----------------

__global__ void xconv_kernel(const float* __restrict__ x, unsigned short* __restrict__ xc, int n) {
    int i = blockIdx.x * 256 + threadIdx.x;
    if (i >= n * 32) return;
    int node = i >> 5, fb = (i & 31) * 4;
    float4 v = *(const float4*)(x + (size_t)node * NFEAT + fb);
    unsigned short h0 = f2bf(v.x), h1 = f2bf(v.y), h2 = f2bf(v.z), h3 = f2bf(v.w);
    uint2 hw;
    hw.x = (unsigned int)h0 | ((unsigned int)h1 << 16);
    hw.y = (unsigned int)h2 | ((unsigned int)h3 << 16);
    *(uint2*)(xc + (size_t)node * RS + fb) = hw;
    unsigned short l0 = f2bf(v.x - bf2f(h0)), l1 = f2bf(v.y - bf2f(h1));
    unsigned short l2 = f2bf(v.z - bf2f(h2)), l3 = f2bf(v.w - bf2f(h3));
    uint2 lw;
    lw.x = (unsigned int)l0 | ((unsigned int)l1 << 16);
    lw.y = (unsigned int)l2 | ((unsigned int)l3 << 16);
    *(uint2*)(xc + (size_t)node * RS + 128 + fb) = lw;
}

// W -> transposed K-major cat [nout][256], H plane only, PRE-SWIZZLED:
// element (c,k) stored at c*256 + (k ^ ((c&7)<<3)). A linear 32KB copy of a
// 64-col slice into LDS then yields the bank-uniform layout the GEMM reads.
__global__ void wconv_kernel(const float* __restrict__ Wl, const float* __restrict__ Wr,
                             unsigned short* __restrict__ Wsz, int nout) {
    int idx = blockIdx.x * 256 + threadIdx.x;
    if (idx >= nout * 256) return;
    int c = idx >> 8, k = idx & 255;
    float f = (k < 128) ? Wl[k * nout + c] : Wr[(k - 128) * nout + c];
    Wsz[c * 256 + (k ^ ((c & 7) << 3))] = f2bf(f);
}

// ---------------- mean aggregation (CSR gather, H-plane only) ----------------
__global__ void agg_kernel(const unsigned short* __restrict__ in,
                           const int* __restrict__ row_ptr, const int* __restrict__ col_idx,
                           const float* __restrict__ inv_deg,
                           unsigned short* __restrict__ agg, int n) {
    int lane = threadIdx.x & 31;
    int node = blockIdx.x * 8 + (threadIdx.x >> 5);
    if (node >= n) return;
    int beg = row_ptr[node], end = row_ptr[node + 1];
    float a[8][4];
    #pragma unroll
    for (int u = 0; u < 8; ++u)
        #pragma unroll
        for (int j = 0; j < 4; ++j) a[u][j] = 0.f;
    auto acc4 = [&](float* a4, uint2 v) {
        a4[0] += bfhi2f(v.x << 16); a4[1] += bfhi2f(v.x & 0xFFFF0000u);
        a4[2] += bfhi2f(v.y << 16); a4[3] += bfhi2f(v.y & 0xFFFF0000u);
    };
    int e = beg;
    for (; e + 8 <= end; e += 8) {
        uint2 v[8];
        #pragma unroll
        for (int u = 0; u < 8; ++u) {
            int s = col_idx[e + u];
            v[u] = ((const uint2*)(in + (size_t)s * RS))[lane];
        }
        #pragma unroll
        for (int u = 0; u < 8; ++u) acc4(a[u], v[u]);
    }
    for (; e < end; ++e) {
        int s = col_idx[e];
        uint2 v = ((const uint2*)(in + (size_t)s * RS))[lane];
        acc4(a[0], v);
    }
    float s4[4];
    #pragma unroll
    for (int j = 0; j < 4; ++j)
        s4[j] = ((a[0][j] + a[1][j]) + (a[2][j] + a[3][j]))
              + ((a[4][j] + a[5][j]) + (a[6][j] + a[7][j]));
    float sc = inv_deg[node];
    unsigned short hs[4], ls[4];
    #pragma unroll
    for (int j = 0; j < 4; ++j) {
        float v = s4[j] * sc;
        hs[j] = f2bf(v);
        ls[j] = f2bf(v - bf2f(hs[j]));
    }
    uint2 hv, lv;
    hv.x = (unsigned int)hs[0] | ((unsigned int)hs[1] << 16);
    hv.y = (unsigned int)hs[2] | ((unsigned int)hs[3] << 16);
    lv.x = (unsigned int)ls[0] | ((unsigned int)ls[1] << 16);
    lv.y = (unsigned int)ls[2] | ((unsigned int)ls[3] << 16);
    *(uint2*)(agg + (size_t)node * RS + lane * 4)       = hv;
    *(uint2*)(agg + (size_t)node * RS + 128 + lane * 4) = lv;
}

// ---------------- MFMA GEMM: C = [agg|x] @ W_hi + b, split-A bf16 ----------------
// Round-8 structure (rounds 4-7 lesson: RA rematerializes register-resident B
// no matter what; stop fighting, use LDS). Block = 4 waves (2 row x 2 col) =
// 64 rows x 64 cols; W tile (64 cols x 256 k, H only) = 32 KB LDS, swizzled so
// b128 B-frag reads are bank-uniform. 2 products per frag (Ah@Wh + Al@Wh); the
// Ah@Wl term (~2^-9 rel) is dropped -- absmax budget 0.0825 vs measured 0.0156.
// A global loads + B ds_reads prefetched one kstep ahead.

template<int NOUT, bool RELU, bool FINAL>
__global__ __launch_bounds__(256, 4) void mfma_gemm(
    const unsigned short* __restrict__ aggc, const unsigned short* __restrict__ xc,
    const unsigned short* __restrict__ Wsz, const float* __restrict__ bias,
    float* __restrict__ outF, unsigned short* __restrict__ outC, int n)
{
    __shared__ char smem[32768];
    const int tid  = threadIdx.x;
    const int wid  = tid >> 6, lane = tid & 63;
    const int wc   = wid & 1,  wr   = wid >> 1;
    const int colTile = blockIdx.y * 64;

    // stage W tile: linear 32KB copy (source pre-swizzled by wconv)
    {
        const float4* src = (const float4*)(Wsz + (size_t)colTile * 256);
        float4* dst = (float4*)smem;
        #pragma unroll
        for (int i = 0; i < 8; ++i)
            dst[i * 256 + tid] = src[i * 256 + tid];
    }
    __syncthreads();

    const int lrow = lane & 15;
    const int lk   = (lane >> 4) * 8;
    const int lkb  = (lane >> 4) * 16;

    const int rowBase = blockIdx.x * 64 + wr * 32;
    int r0 = rowBase + lrow;      if (r0 > n - 1) r0 = n - 1;
    int r1 = rowBase + 16 + lrow; if (r1 > n - 1) r1 = n - 1;

    // B-frag LDS addressing: byte = (cc*512 + ks*64 + lkb) ^ ((cc&7)<<4)
    int cbase[2], xmask[2];
    #pragma unroll
    for (int nf = 0; nf < 2; ++nf) {
        int cc = wc * 32 + nf * 16 + lrow;
        cbase[nf] = (cc << 9) + lkb;
        xmask[nf] = (cc & 7) << 4;
    }

    f32x4 acc[2][2];
    #pragma unroll
    for (int mf = 0; mf < 2; ++mf)
        #pragma unroll
        for (int nf = 0; nf < 2; ++nf)
            acc[mf][nf] = (f32x4){0.f, 0.f, 0.f, 0.f};

    const unsigned short* Ar0 = aggc + (size_t)r0 * RS;
    const unsigned short* Ar1 = aggc + (size_t)r1 * RS;
    const unsigned short* Xr0 = xc   + (size_t)r0 * RS;
    const unsigned short* Xr1 = xc   + (size_t)r1 * RS;

    // prefetch kstep 0
    bf16x8 a0h = *(const bf16x8*)(Ar0 + lk);
    bf16x8 a1h = *(const bf16x8*)(Ar1 + lk);
    bf16x8 a0l = *(const bf16x8*)(Ar0 + 128 + lk);
    bf16x8 a1l = *(const bf16x8*)(Ar1 + 128 + lk);
    bf16x8 b0  = *(const bf16x8*)(smem + (cbase[0] ^ xmask[0]));
    bf16x8 b1  = *(const bf16x8*)(smem + (cbase[1] ^ xmask[1]));

    #pragma unroll
    for (int ks = 0; ks < 8; ++ks) {
        bf16x8 c0h = a0h, c1h = a1h, c0l = a0l, c1l = a1l, d0 = b0, d1 = b1;
        if (ks < 7) {
            const int ksn = ks + 1;
            const unsigned short* P0 = (ksn < 4) ? Ar0 : Xr0;
            const unsigned short* P1 = (ksn < 4) ? Ar1 : Xr1;
            const int kk = (ksn & 3) * 32 + lk;
            a0h = *(const bf16x8*)(P0 + kk);
            a1h = *(const bf16x8*)(P1 + kk);
            a0l = *(const bf16x8*)(P0 + 128 + kk);
            a1l = *(const bf16x8*)(P1 + 128 + kk);
            b0  = *(const bf16x8*)(smem + ((cbase[0] + (ksn << 6)) ^ xmask[0]));
            b1  = *(const bf16x8*)(smem + ((cbase[1] + (ksn << 6)) ^ xmask[1]));
        }
        acc[0][0] = __builtin_amdgcn_mfma_f32_16x16x32_bf16(c0h, d0, acc[0][0], 0, 0, 0);
        acc[0][0] = __builtin_amdgcn_mfma_f32_16x16x32_bf16(c0l, d0, acc[0][0], 0, 0, 0);
        acc[1][0] = __builtin_amdgcn_mfma_f32_16x16x32_bf16(c1h, d0, acc[1][0], 0, 0, 0);
        acc[1][0] = __builtin_amdgcn_mfma_f32_16x16x32_bf16(c1l, d0, acc[1][0], 0, 0, 0);
        acc[0][1] = __builtin_amdgcn_mfma_f32_16x16x32_bf16(c0h, d1, acc[0][1], 0, 0, 0);
        acc[0][1] = __builtin_amdgcn_mfma_f32_16x16x32_bf16(c0l, d1, acc[0][1], 0, 0, 0);
        acc[1][1] = __builtin_amdgcn_mfma_f32_16x16x32_bf16(c1h, d1, acc[1][1], 0, 0, 0);
        acc[1][1] = __builtin_amdgcn_mfma_f32_16x16x32_bf16(c1l, d1, acc[1][1], 0, 0, 0);
    }

    // epilogue: bias (+ReLU); FINAL -> fp32 out, else -> combined H|L plane
    #pragma unroll
    for (int mf = 0; mf < 2; ++mf) {
        #pragma unroll
        for (int nf = 0; nf < 2; ++nf) {
            const int c = colTile + wc * 32 + nf * 16 + lrow;
            const float bv = bias[c];
            #pragma unroll
            for (int reg = 0; reg < 4; ++reg) {
                const int r = rowBase + mf * 16 + (lane >> 4) * 4 + reg;
                if (r < n) {
                    float h = acc[mf][nf][reg] + bv;
                    if (RELU) h = fmaxf(h, 0.f);
                    if (FINAL) {
                        outF[(size_t)r * NOUT + c] = h;
                    } else {
                        unsigned short hi = f2bf(h);
                        outC[(size_t)r * RS + c]       = hi;
                        outC[(size_t)r * RS + 128 + c] = f2bf(h - bf2f(hi));
                    }
                }
            }
        }
    }
}

extern "C" void kernel_launch(void* const* d_in, const int* in_sizes, int n_in,
                              void* d_out, int out_size, void* d_ws, size_t ws_size,
                              hipStream_t stream) {
    const float* x   = (const float*)d_in[0];
    const int*   ei  = (const int*)d_in[1];
    const float* Wl0 = (const float*)d_in[2];
    const float* Wr0 = (const float*)d_in[3];
    const float* b0  = (const float*)d_in[4];
    const float* Wl1 = (const float*)d_in[5];
    const float* Wr1 = (const float*)d_in[6];
    const float* b1  = (const float*)d_in[7];
    const float* Wl2 = (const float*)d_in[8];
    const float* Wr2 = (const float*)d_in[9];
    const float* b2  = (const float*)d_in[10];

    const int nN = in_sizes[0] / NFEAT;       // 50000
    const int nE = in_sizes[1] / 2;           // 800000
    const int* src = ei;
    const int* dst = ei + nE;

    char* ws = (char*)d_ws;
    size_t off = 0;
    auto take = [&](size_t bytes) { char* p = ws + off; off += (bytes + 255) & ~(size_t)255; return p; };
    int*   cnt      = (int*)  take((size_t)nN * 4);
    int*   row_ptr  = (int*)  take((size_t)(nN + 1) * 4);
    int*   col_idx  = (int*)  take((size_t)nE * 4);
    float* inv_deg  = (float*)take((size_t)nN * 4);
    int*   blockSum = (int*)  take(256 * 4);
    const size_t plane = (size_t)nN * RS * 2;
    unsigned short* aggC = (unsigned short*)take(plane);
    unsigned short* xc0  = (unsigned short*)take(plane);
    unsigned short* xc1  = (unsigned short*)take(plane);
    unsigned short* Wsz0 = (unsigned short*)take(128 * 256 * 2);
    unsigned short* Wsz1 = (unsigned short*)take(128 * 256 * 2);
    unsigned short* Wsz2 = (unsigned short*)take(64 * 256 * 2);
    (void)ws_size; (void)n_in; (void)out_size;

    const int scanBlocks = (nN + 255) / 256;

    // CSR build
    hipMemsetAsync(cnt, 0, (size_t)nN * 4, stream);
    hist_kernel<<<(nE + 255) / 256, 256, 0, stream>>>(dst, cnt, nE);
    blocksum_kernel<<<scanBlocks, 256, 0, stream>>>(cnt, blockSum, nN);
    scan_write_kernel<<<scanBlocks, 256, 0, stream>>>(cnt, blockSum, row_ptr, inv_deg, nN);
    fill_kernel<<<(nE + 255) / 256, 256, 0, stream>>>(src, dst, cnt, col_idx, nE);

    // conversions
    xconv_kernel<<<(nN * 32 + 255) / 256, 256, 0, stream>>>(x, xc0, nN);
    wconv_kernel<<<(128 * 256 + 255) / 256, 256, 0, stream>>>(Wl0, Wr0, Wsz0, 128);
    wconv_kernel<<<(128 * 256 + 255) / 256, 256, 0, stream>>>(Wl1, Wr1, Wsz1, 128);
    wconv_kernel<<<(64 * 256 + 255) / 256, 256, 0, stream>>>(Wl2, Wr2, Wsz2, 64);

    const int aggGrid = (nN + 7) / 8;
    const dim3 gBig((nN + 63) / 64, 2);
    const dim3 gFin((nN + 63) / 64, 1);

    // layer 0: x -> h0
    agg_kernel<<<aggGrid, 256, 0, stream>>>(xc0, row_ptr, col_idx, inv_deg, aggC, nN);
    mfma_gemm<128, true, false><<<gBig, 256, 0, stream>>>(
        aggC, xc0, Wsz0, b0, nullptr, xc1, nN);
    // layer 1: h0 -> h1
    agg_kernel<<<aggGrid, 256, 0, stream>>>(xc1, row_ptr, col_idx, inv_deg, aggC, nN);
    mfma_gemm<128, true, false><<<gBig, 256, 0, stream>>>(
        aggC, xc1, Wsz1, b1, nullptr, xc0, nN);
    // layer 2: h1 -> out (fp32)
    agg_kernel<<<aggGrid, 256, 0, stream>>>(xc0, row_ptr, col_idx, inv_deg, aggC, nN);
    mfma_gemm<64, false, true><<<gFin, 256, 0, stream>>>(
        aggC, xc0, Wsz2, b2, (float*)d_out, nullptr, nN);
}

// Round 9
// 309.674 us; speedup vs baseline: 1.3648x; 1.0236x over previous
//
#include <hip/hip_runtime.h>

#define NFEAT 128
#define RS 256   // combined-plane row stride in shorts: [0,128)=H, [128,256)=L

using bf16x8 = __attribute__((ext_vector_type(8))) short;
using f32x4  = __attribute__((ext_vector_type(4))) float;

__device__ __forceinline__ float bf2f(unsigned short u) {
    union { unsigned int i; float f; } v; v.i = ((unsigned int)u) << 16; return v.f;
}
__device__ __forceinline__ float bfhi2f(unsigned int hi16) {
    union { unsigned int i; float f; } v; v.i = hi16; return v.f;
}
__device__ __forceinline__ unsigned short f2bf(float f) {      // RNE
    union { float f; unsigned int i; } v; v.f = f;
    unsigned int i = v.i;
    return (unsigned short)((i + 0x7FFFu + ((i >> 16) & 1u)) >> 16);
}

// ---------------- CSR build (XCD-sliced hist/fill) ----------------
// Round-9: blocks with the same (blockIdx & 7) land on the same XCD (empirical
// round-robin, same assumption as T1 swizzle). Each slice-group scans ALL edges
// (8x coalesced reads -- cheap) but only touches cnt/col_idx in its own 1/8
// node range, so atomics and scattered writes stay in ONE XCD's L2 and merge.
// Correctness does not depend on the bid->XCD mapping, only locality does.

__global__ void hist_kernel(const int* __restrict__ dst, int* __restrict__ cnt,
                            int nE, int sliceN) {
    const int slice = blockIdx.x & 7;
    const int lo = slice * sliceN, hi = lo + sliceN;
    const int nb = gridDim.x >> 3;
    const int bs = blockIdx.x >> 3;
    for (int i = bs * 256 + threadIdx.x; i < nE; i += nb * 256) {
        int d = dst[i];
        if (d >= lo && d < hi) atomicAdd(&cnt[d], 1);
    }
}

__global__ void fill_kernel(const int* __restrict__ src, const int* __restrict__ dst,
                            int* __restrict__ cnt, int* __restrict__ col_idx,
                            int nE, int sliceN) {
    const int slice = blockIdx.x & 7;
    const int lo = slice * sliceN, hi = lo + sliceN;
    const int nb = gridDim.x >> 3;
    const int bs = blockIdx.x >> 3;
    for (int i = bs * 256 + threadIdx.x; i < nE; i += nb * 256) {
        int d = dst[i];
        int s = src[i];
        if (d >= lo && d < hi) {
            int pos = atomicAdd(&cnt[d], 1);
            col_idx[pos] = s;
        }
    }
}

__global__ void blocksum_kernel(const int* __restrict__ cnt, int* __restrict__ blockSum, int n) {
    int i = blockIdx.x * 256 + threadIdx.x;
    int d = (i < n) ? cnt[i] : 0;
    int lane = threadIdx.x & 63, wid = threadIdx.x >> 6;
    __shared__ int ws[4];
    int v = d;
    for (int off = 32; off; off >>= 1) v += __shfl_down(v, off);
    if (lane == 0) ws[wid] = v;
    __syncthreads();
    if (threadIdx.x == 0) blockSum[blockIdx.x] = ws[0] + ws[1] + ws[2] + ws[3];
}

__global__ void scan_write_kernel(int* __restrict__ cnt, const int* __restrict__ blockSum,
                                  int* __restrict__ row_ptr, float* __restrict__ inv_deg,
                                  int n) {
    const int b = blockIdx.x, tid = threadIdx.x;
    const int lane = tid & 63, wid = tid >> 6;
    __shared__ int wsA[4];
    __shared__ int wsB[4];
    int v = (tid < b) ? blockSum[tid] : 0;
    for (int off = 32; off; off >>= 1) v += __shfl_down(v, off);
    if (lane == 0) wsA[wid] = v;
    int i = b * 256 + tid;
    int d = (i < n) ? cnt[i] : 0;
    int s = d;
    for (int off = 1; off < 64; off <<= 1) {
        int t = __shfl_up(s, off);
        if (lane >= off) s += t;
    }
    if (lane == 63) wsB[wid] = s;
    __syncthreads();
    int blockOff = wsA[0] + wsA[1] + wsA[2] + wsA[3];
    int wOff = 0;
    for (int w = 0; w < wid; ++w) wOff += wsB[w];
    int excl = blockOff + wOff + s - d;
    if (i < n) {
        row_ptr[i] = excl;
        cnt[i]     = excl;
        inv_deg[i] = 1.0f / (float)(d > 1 ? d : 1);
    }
    if (i == n) row_ptr[n] = excl;
}

// ---------------- conversions ----------------

__global__ void xconv_kernel(const float* __restrict__ x, unsigned short* __restrict__ xc, int n) {
    int i = blockIdx.x * 256 + threadIdx.x;
    if (i >= n * 32) return;
    int node = i >> 5, fb = (i & 31) * 4;
    float4 v = *(const float4*)(x + (size_t)node * NFEAT + fb);
    unsigned short h0 = f2bf(v.x), h1 = f2bf(v.y), h2 = f2bf(v.z), h3 = f2bf(v.w);
    uint2 hw;
    hw.x = (unsigned int)h0 | ((unsigned int)h1 << 16);
    hw.y = (unsigned int)h2 | ((unsigned int)h3 << 16);
    *(uint2*)(xc + (size_t)node * RS + fb) = hw;
    unsigned short l0 = f2bf(v.x - bf2f(h0)), l1 = f2bf(v.y - bf2f(h1));
    unsigned short l2 = f2bf(v.z - bf2f(h2)), l3 = f2bf(v.w - bf2f(h3));
    uint2 lw;
    lw.x = (unsigned int)l0 | ((unsigned int)l1 << 16);
    lw.y = (unsigned int)l2 | ((unsigned int)l3 << 16);
    *(uint2*)(xc + (size_t)node * RS + 128 + fb) = lw;
}

// W -> transposed K-major cat [nout][256], H plane only, PRE-SWIZZLED:
// element (c,k) stored at c*256 + (k ^ ((c&7)<<3)).
__global__ void wconv_kernel(const float* __restrict__ Wl, const float* __restrict__ Wr,
                             unsigned short* __restrict__ Wsz, int nout) {
    int idx = blockIdx.x * 256 + threadIdx.x;
    if (idx >= nout * 256) return;
    int c = idx >> 8, k = idx & 255;
    float f = (k < 128) ? Wl[k * nout + c] : Wr[(k - 128) * nout + c];
    Wsz[c * 256 + (k ^ ((c & 7) << 3))] = f2bf(f);
}

// ---------------- mean aggregation (CSR gather, H-plane, uint4) ----------------
// Round-9: 16 lanes/node x uint4 (8 feats per 16B load) -- halves VMEM
// instruction count vs 32-lane uint2 (round-8 analysis: agg was VMEM-issue
// bound, 25.6M loads / 256 CU / ~1 per cyc ~= 42us). Unroll 8, 4 accum sets.
__global__ void agg_kernel(const unsigned short* __restrict__ in,
                           const int* __restrict__ row_ptr, const int* __restrict__ col_idx,
                           const float* __restrict__ inv_deg,
                           unsigned short* __restrict__ agg, int n) {
    int lane = threadIdx.x & 15;                    // feature block [lane*8, lane*8+8)
    int node = blockIdx.x * 16 + (threadIdx.x >> 4);
    if (node >= n) return;
    int beg = row_ptr[node], end = row_ptr[node + 1];
    float a[4][8];
    #pragma unroll
    for (int u = 0; u < 4; ++u)
        #pragma unroll
        for (int j = 0; j < 8; ++j) a[u][j] = 0.f;
    auto acc8 = [&](float* A, uint4 v) {
        A[0] += bfhi2f(v.x << 16); A[1] += bfhi2f(v.x & 0xFFFF0000u);
        A[2] += bfhi2f(v.y << 16); A[3] += bfhi2f(v.y & 0xFFFF0000u);
        A[4] += bfhi2f(v.z << 16); A[5] += bfhi2f(v.z & 0xFFFF0000u);
        A[6] += bfhi2f(v.w << 16); A[7] += bfhi2f(v.w & 0xFFFF0000u);
    };
    int e = beg;
    for (; e + 8 <= end; e += 8) {
        uint4 v[8];
        #pragma unroll
        for (int u = 0; u < 8; ++u) {
            int s = col_idx[e + u];
            v[u] = *(const uint4*)(in + (size_t)s * RS + lane * 8);
        }
        #pragma unroll
        for (int u = 0; u < 8; ++u) acc8(a[u & 3], v[u]);
    }
    for (; e < end; ++e) {
        int s = col_idx[e];
        uint4 v = *(const uint4*)(in + (size_t)s * RS + lane * 8);
        acc8(a[0], v);
    }
    float sc = inv_deg[node];
    unsigned short hs[8], ls[8];
    #pragma unroll
    for (int j = 0; j < 8; ++j) {
        float m = ((a[0][j] + a[1][j]) + (a[2][j] + a[3][j])) * sc;
        hs[j] = f2bf(m);
        ls[j] = f2bf(m - bf2f(hs[j]));
    }
    uint4 hv, lv;
    hv.x = (unsigned int)hs[0] | ((unsigned int)hs[1] << 16);
    hv.y = (unsigned int)hs[2] | ((unsigned int)hs[3] << 16);
    hv.z = (unsigned int)hs[4] | ((unsigned int)hs[5] << 16);
    hv.w = (unsigned int)hs[6] | ((unsigned int)hs[7] << 16);
    lv.x = (unsigned int)ls[0] | ((unsigned int)ls[1] << 16);
    lv.y = (unsigned int)ls[2] | ((unsigned int)ls[3] << 16);
    lv.z = (unsigned int)ls[4] | ((unsigned int)ls[5] << 16);
    lv.w = (unsigned int)ls[6] | ((unsigned int)ls[7] << 16);
    *(uint4*)(agg + (size_t)node * RS + lane * 8)       = hv;
    *(uint4*)(agg + (size_t)node * RS + 128 + lane * 8) = lv;
}

// ---------------- MFMA GEMM: C = [agg|x] @ W_hi + b, split-A bf16 ----------------
// Block = 4 waves (2 row x 2 col) = 64 rows x 64 cols; W tile (64 cols x 256 k,
// H only) = 32 KB LDS, swizzled so b128 B-frag reads are bank-uniform.
// 2 products per frag (Ah@Wh + Al@Wh); Ah@Wl (~2^-9 rel) dropped.

template<int NOUT, bool RELU, bool FINAL>
__global__ __launch_bounds__(256, 4) void mfma_gemm(
    const unsigned short* __restrict__ aggc, const unsigned short* __restrict__ xc,
    const unsigned short* __restrict__ Wsz, const float* __restrict__ bias,
    float* __restrict__ outF, unsigned short* __restrict__ outC, int n)
{
    __shared__ char smem[32768];
    const int tid  = threadIdx.x;
    const int wid  = tid >> 6, lane = tid & 63;
    const int wc   = wid & 1,  wr   = wid >> 1;
    const int colTile = blockIdx.y * 64;

    {
        const float4* src = (const float4*)(Wsz + (size_t)colTile * 256);
        float4* dst = (float4*)smem;
        #pragma unroll
        for (int i = 0; i < 8; ++i)
            dst[i * 256 + tid] = src[i * 256 + tid];
    }
    __syncthreads();

    const int lrow = lane & 15;
    const int lk   = (lane >> 4) * 8;
    const int lkb  = (lane >> 4) * 16;

    const int rowBase = blockIdx.x * 64 + wr * 32;
    int r0 = rowBase + lrow;      if (r0 > n - 1) r0 = n - 1;
    int r1 = rowBase + 16 + lrow; if (r1 > n - 1) r1 = n - 1;

    int cbase[2], xmask[2];
    #pragma unroll
    for (int nf = 0; nf < 2; ++nf) {
        int cc = wc * 32 + nf * 16 + lrow;
        cbase[nf] = (cc << 9) + lkb;
        xmask[nf] = (cc & 7) << 4;
    }

    f32x4 acc[2][2];
    #pragma unroll
    for (int mf = 0; mf < 2; ++mf)
        #pragma unroll
        for (int nf = 0; nf < 2; ++nf)
            acc[mf][nf] = (f32x4){0.f, 0.f, 0.f, 0.f};

    const unsigned short* Ar0 = aggc + (size_t)r0 * RS;
    const unsigned short* Ar1 = aggc + (size_t)r1 * RS;
    const unsigned short* Xr0 = xc   + (size_t)r0 * RS;
    const unsigned short* Xr1 = xc   + (size_t)r1 * RS;

    bf16x8 a0h = *(const bf16x8*)(Ar0 + lk);
    bf16x8 a1h = *(const bf16x8*)(Ar1 + lk);
    bf16x8 a0l = *(const bf16x8*)(Ar0 + 128 + lk);
    bf16x8 a1l = *(const bf16x8*)(Ar1 + 128 + lk);
    bf16x8 b0  = *(const bf16x8*)(smem + (cbase[0] ^ xmask[0]));
    bf16x8 b1  = *(const bf16x8*)(smem + (cbase[1] ^ xmask[1]));

    #pragma unroll
    for (int ks = 0; ks < 8; ++ks) {
        bf16x8 c0h = a0h, c1h = a1h, c0l = a0l, c1l = a1l, d0 = b0, d1 = b1;
        if (ks < 7) {
            const int ksn = ks + 1;
            const unsigned short* P0 = (ksn < 4) ? Ar0 : Xr0;
            const unsigned short* P1 = (ksn < 4) ? Ar1 : Xr1;
            const int kk = (ksn & 3) * 32 + lk;
            a0h = *(const bf16x8*)(P0 + kk);
            a1h = *(const bf16x8*)(P1 + kk);
            a0l = *(const bf16x8*)(P0 + 128 + kk);
            a1l = *(const bf16x8*)(P1 + 128 + kk);
            b0  = *(const bf16x8*)(smem + ((cbase[0] + (ksn << 6)) ^ xmask[0]));
            b1  = *(const bf16x8*)(smem + ((cbase[1] + (ksn << 6)) ^ xmask[1]));
        }
        acc[0][0] = __builtin_amdgcn_mfma_f32_16x16x32_bf16(c0h, d0, acc[0][0], 0, 0, 0);
        acc[0][0] = __builtin_amdgcn_mfma_f32_16x16x32_bf16(c0l, d0, acc[0][0], 0, 0, 0);
        acc[1][0] = __builtin_amdgcn_mfma_f32_16x16x32_bf16(c1h, d0, acc[1][0], 0, 0, 0);
        acc[1][0] = __builtin_amdgcn_mfma_f32_16x16x32_bf16(c1l, d0, acc[1][0], 0, 0, 0);
        acc[0][1] = __builtin_amdgcn_mfma_f32_16x16x32_bf16(c0h, d1, acc[0][1], 0, 0, 0);
        acc[0][1] = __builtin_amdgcn_mfma_f32_16x16x32_bf16(c0l, d1, acc[0][1], 0, 0, 0);
        acc[1][1] = __builtin_amdgcn_mfma_f32_16x16x32_bf16(c1h, d1, acc[1][1], 0, 0, 0);
        acc[1][1] = __builtin_amdgcn_mfma_f32_16x16x32_bf16(c1l, d1, acc[1][1], 0, 0, 0);
    }

    #pragma unroll
    for (int mf = 0; mf < 2; ++mf) {
        #pragma unroll
        for (int nf = 0; nf < 2; ++nf) {
            const int c = colTile + wc * 32 + nf * 16 + lrow;
            const float bv = bias[c];
            #pragma unroll
            for (int reg = 0; reg < 4; ++reg) {
                const int r = rowBase + mf * 16 + (lane >> 4) * 4 + reg;
                if (r < n) {
                    float h = acc[mf][nf][reg] + bv;
                    if (RELU) h = fmaxf(h, 0.f);
                    if (FINAL) {
                        outF[(size_t)r * NOUT + c] = h;
                    } else {
                        unsigned short hi = f2bf(h);
                        outC[(size_t)r * RS + c]       = hi;
                        outC[(size_t)r * RS + 128 + c] = f2bf(h - bf2f(hi));
                    }
                }
            }
        }
    }
}

extern "C" void kernel_launch(void* const* d_in, const int* in_sizes, int n_in,
                              void* d_out, int out_size, void* d_ws, size_t ws_size,
                              hipStream_t stream) {
    const float* x   = (const float*)d_in[0];
    const int*   ei  = (const int*)d_in[1];
    const float* Wl0 = (const float*)d_in[2];
    const float* Wr0 = (const float*)d_in[3];
    const float* b0  = (const float*)d_in[4];
    const float* Wl1 = (const float*)d_in[5];
    const float* Wr1 = (const float*)d_in[6];
    const float* b1  = (const float*)d_in[7];
    const float* Wl2 = (const float*)d_in[8];
    const float* Wr2 = (const float*)d_in[9];
    const float* b2  = (const float*)d_in[10];

    const int nN = in_sizes[0] / NFEAT;       // 50000
    const int nE = in_sizes[1] / 2;           // 800000
    const int* src = ei;
    const int* dst = ei + nE;

    char* ws = (char*)d_ws;
    size_t off = 0;
    auto take = [&](size_t bytes) { char* p = ws + off; off += (bytes + 255) & ~(size_t)255; return p; };
    int*   cnt      = (int*)  take((size_t)nN * 4);
    int*   row_ptr  = (int*)  take((size_t)(nN + 1) * 4);
    int*   col_idx  = (int*)  take((size_t)nE * 4);
    float* inv_deg  = (float*)take((size_t)nN * 4);
    int*   blockSum = (int*)  take(256 * 4);
    const size_t plane = (size_t)nN * RS * 2;
    unsigned short* aggC = (unsigned short*)take(plane);
    unsigned short* xc0  = (unsigned short*)take(plane);
    unsigned short* xc1  = (unsigned short*)take(plane);
    unsigned short* Wsz0 = (unsigned short*)take(128 * 256 * 2);
    unsigned short* Wsz1 = (unsigned short*)take(128 * 256 * 2);
    unsigned short* Wsz2 = (unsigned short*)take(64 * 256 * 2);
    (void)ws_size; (void)n_in; (void)out_size;

    const int scanBlocks = (nN + 255) / 256;
    const int sliceN = (nN + 7) / 8;          // 6250 nodes per XCD slice

    // CSR build (XCD-sliced hist/fill)
    hipMemsetAsync(cnt, 0, (size_t)nN * 4, stream);
    hist_kernel<<<2048, 256, 0, stream>>>(dst, cnt, nE, sliceN);
    blocksum_kernel<<<scanBlocks, 256, 0, stream>>>(cnt, blockSum, nN);
    scan_write_kernel<<<scanBlocks, 256, 0, stream>>>(cnt, blockSum, row_ptr, inv_deg, nN);
    fill_kernel<<<2048, 256, 0, stream>>>(src, dst, cnt, col_idx, nE, sliceN);

    // conversions
    xconv_kernel<<<(nN * 32 + 255) / 256, 256, 0, stream>>>(x, xc0, nN);
    wconv_kernel<<<(128 * 256 + 255) / 256, 256, 0, stream>>>(Wl0, Wr0, Wsz0, 128);
    wconv_kernel<<<(128 * 256 + 255) / 256, 256, 0, stream>>>(Wl1, Wr1, Wsz1, 128);
    wconv_kernel<<<(64 * 256 + 255) / 256, 256, 0, stream>>>(Wl2, Wr2, Wsz2, 64);

    const int aggGrid = (nN + 15) / 16;
    const dim3 gBig((nN + 63) / 64, 2);
    const dim3 gFin((nN + 63) / 64, 1);

    // layer 0: x -> h0
    agg_kernel<<<aggGrid, 256, 0, stream>>>(xc0, row_ptr, col_idx, inv_deg, aggC, nN);
    mfma_gemm<128, true, false><<<gBig, 256, 0, stream>>>(
        aggC, xc0, Wsz0, b0, nullptr, xc1, nN);
    // layer 1: h0 -> h1
    agg_kernel<<<aggGrid, 256, 0, stream>>>(xc1, row_ptr, col_idx, inv_deg, aggC, nN);
    mfma_gemm<128, true, false><<<gBig, 256, 0, stream>>>(
        aggC, xc1, Wsz1, b1, nullptr, xc0, nN);
    // layer 2: h1 -> out (fp32)
    agg_kernel<<<aggGrid, 256, 0, stream>>>(xc0, row_ptr, col_idx, inv_deg, aggC, nN);
    mfma_gemm<64, false, true><<<gFin, 256, 0, stream>>>(
        aggC, xc0, Wsz2, b2, (float*)d_out, nullptr, nN);
}